// Round 2
// baseline (303.292 us; speedup 1.0000x reference)
//
#include <hip/hip_runtime.h>

#define NBINS   256
#define B       64
#define NPB     786432          // 3*512*512 elements per batch
#define NF4     (NPB / 4)       // 196608 float4 per batch
#define BPB1    32              // k1 blocks per batch  -> 2048 blocks, 24 iters/thread
#define BPB2    16              // k2 blocks per batch  -> 1024 blocks, 48 iters/thread
#define THREADS 256

// ---------------------------------------------------------------------------
// k1: per-block min/max partials (no atomics, no init needed)
// ---------------------------------------------------------------------------
__global__ __launch_bounds__(THREADS) void k_minmax(const float4* __restrict__ x,
                                                    float* __restrict__ pmn,
                                                    float* __restrict__ pmx) {
    const int batch = blockIdx.x / BPB1;
    const int blk   = blockIdx.x % BPB1;
    const float4* p = x + (long long)batch * NF4;

    float mn = 3.402823466e38f, mx = -3.402823466e38f;
    // NF4 / (BPB1*THREADS) = 24 exact, no tail
    #pragma unroll 4
    for (int i = blk * THREADS + threadIdx.x; i < NF4; i += BPB1 * THREADS) {
        float4 v = p[i];
        mn = fminf(mn, fminf(fminf(v.x, v.y), fminf(v.z, v.w)));
        mx = fmaxf(mx, fmaxf(fmaxf(v.x, v.y), fmaxf(v.z, v.w)));
    }
    for (int o = 32; o > 0; o >>= 1) {
        mn = fminf(mn, __shfl_down(mn, o));
        mx = fmaxf(mx, __shfl_down(mx, o));
    }
    __shared__ float smn[4], smx[4];
    int wid = threadIdx.x >> 6;
    if ((threadIdx.x & 63) == 0) { smn[wid] = mn; smx[wid] = mx; }
    __syncthreads();
    if (threadIdx.x == 0) {
        pmn[blockIdx.x] = fminf(fminf(smn[0], smn[1]), fminf(smn[2], smn[3]));
        pmx[blockIdx.x] = fmaxf(fmaxf(smx[0], smx[1]), fmaxf(smx[2], smx[3]));
    }
}

// ---------------------------------------------------------------------------
// k2: per-block partial histogram. 32 LDS replicas in TRANSPOSED layout:
//     lh[bin*32 + g] with g = lane%32  =>  bank = g always  =>  zero bank
//     conflicts on the atomics (lane/lane+32 2-way aliasing is free).
// ---------------------------------------------------------------------------
__global__ __launch_bounds__(THREADS) void k_hist(const float4* __restrict__ x,
                                                  const float* __restrict__ pmn,
                                                  const float* __restrict__ pmx,
                                                  unsigned* __restrict__ part) {
    __shared__ unsigned lh[NBINS * 32];      // 32 KB
    __shared__ float s_lo, s_scale;

    const int batch = blockIdx.x / BPB2;
    const int blk   = blockIdx.x % BPB2;

    for (int i = threadIdx.x; i < NBINS * 32; i += THREADS) lh[i] = 0u;

    // First wave reduces this batch's 32 min/max partials (all 64 lanes load
    // a duplicate so the shuffle tree stays defined).
    if (threadIdx.x < 64) {
        int l = threadIdx.x & 31;
        float mn = pmn[batch * BPB1 + l];
        float mx = pmx[batch * BPB1 + l];
        for (int o = 16; o > 0; o >>= 1) {
            mn = fminf(mn, __shfl_down(mn, o));
            mx = fmaxf(mx, __shfl_down(mx, o));
        }
        if (threadIdx.x == 0) {
            // Match reference: rng/lo selection, f32 divide then multiply.
            float rng = (mx > mn) ? (mx - mn) : 2.0f;
            s_lo      = (mx > mn) ? mn : (mn - 1.0f);
            s_scale   = (float)NBINS / rng;
        }
    }
    __syncthreads();

    const float lo    = s_lo;
    const float scale = s_scale;
    const int   g     = threadIdx.x & 31;
    const float4* p   = x + (long long)batch * NF4;

    #pragma unroll 2
    for (int i = blk * THREADS + threadIdx.x; i < NF4; i += BPB2 * THREADS) {
        float4 v = p[i];
        int i0 = min(max((int)((v.x - lo) * scale), 0), NBINS - 1);
        int i1 = min(max((int)((v.y - lo) * scale), 0), NBINS - 1);
        int i2 = min(max((int)((v.z - lo) * scale), 0), NBINS - 1);
        int i3 = min(max((int)((v.w - lo) * scale), 0), NBINS - 1);
        atomicAdd(&lh[i0 * 32 + g], 1u);
        atomicAdd(&lh[i1 * 32 + g], 1u);
        atomicAdd(&lh[i2 * 32 + g], 1u);
        atomicAdd(&lh[i3 * 32 + g], 1u);
    }
    __syncthreads();

    // Merge 32 replicas for bin = tid, rotated so lane L reads bank (j+L)%32:
    // conflict-free. Store per-block partial hist (coalesced).
    unsigned s = 0;
    #pragma unroll
    for (int j = 0; j < 32; ++j)
        s += lh[threadIdx.x * 32 + ((j + threadIdx.x) & 31)];
    part[blockIdx.x * NBINS + threadIdx.x] = s;
}

// ---------------------------------------------------------------------------
// k3: one block per batch — sum 16 partials per bin, entropy reduce.
// ---------------------------------------------------------------------------
__global__ __launch_bounds__(THREADS) void k_ent(const unsigned* __restrict__ part,
                                                 float* __restrict__ ent) {
    const int b = blockIdx.x;
    unsigned c = 0;
    #pragma unroll
    for (int j = 0; j < BPB2; ++j)
        c += part[(b * BPB2 + j) * NBINS + threadIdx.x];

    float s = 0.0f;
    if (c) {
        float pv = (float)c * (1.0f / (float)NPB);
        s = pv * log2f(pv);
    }
    for (int o = 32; o > 0; o >>= 1) s += __shfl_down(s, o);
    __shared__ float sw[4];
    int wid = threadIdx.x >> 6;
    if ((threadIdx.x & 63) == 0) sw[wid] = s;
    __syncthreads();
    if (threadIdx.x == 0)
        ent[b] = -(sw[0] + sw[1] + sw[2] + sw[3]);
}

// ---------------------------------------------------------------------------
// k4: mean over 64 batch entropies -> out[0]
// ---------------------------------------------------------------------------
__global__ __launch_bounds__(64) void k_mean(const float* __restrict__ ent,
                                             float* __restrict__ out) {
    float v = ent[threadIdx.x];
    for (int o = 32; o > 0; o >>= 1) v += __shfl_down(v, o);
    if (threadIdx.x == 0) out[0] = v * (1.0f / (float)B);
}

extern "C" void kernel_launch(void* const* d_in, const int* in_sizes, int n_in,
                              void* d_out, int out_size, void* d_ws, size_t ws_size,
                              hipStream_t stream) {
    const float* x = (const float*)d_in[0];
    float* out = (float*)d_out;

    float*    pmn  = (float*)d_ws;                       // 2048
    float*    pmx  = pmn + B * BPB1;                     // 2048
    unsigned* part = (unsigned*)(pmx + B * BPB1);        // 1024*256
    float*    ent  = (float*)(part + B * BPB2 * NBINS);  // 64

    hipLaunchKernelGGL(k_minmax, dim3(B * BPB1), dim3(THREADS), 0, stream,
                       (const float4*)x, pmn, pmx);
    hipLaunchKernelGGL(k_hist, dim3(B * BPB2), dim3(THREADS), 0, stream,
                       (const float4*)x, pmn, pmx, part);
    hipLaunchKernelGGL(k_ent, dim3(B), dim3(THREADS), 0, stream, part, ent);
    hipLaunchKernelGGL(k_mean, dim3(1), dim3(64), 0, stream, ent, out);
}